// Round 5
// baseline (168.650 us; speedup 1.0000x reference)
//
#include <hip/hip_runtime.h>

#define NUM_NODES   120000
#define NUM_MOVABLE 100000
#define NUM_NETS    100000
#define NUM_PINS    400000
#define NBX 256
#define NBY 256
#define GRID (NBX*NBY)
#define CAP 2048            // per-row bucket capacity (expected max ~1600)

constexpr float BSX      = 1000.0f / 256.0f;   // 3.90625 exact in binary
constexpr float INV_BS   = 256.0f / 1000.0f;
constexpr float BIN_AREA = BSX * BSX;
constexpr float EPSV     = 1e-6f;

// Workspace layout:
//   bbox:    float4[NUM_NETS]       {xmn, ymn, xmx, ymx}
//   count:   u32[256*16]            per-row cursor, line-padded (stride 16)
//   entries: u32[256*CAP]           (net<<1)|side per row bucket
//   A_hT,B_hT,A_vT,B_vT: float[GRID] transposed [y*NBX+x]
//   util:    float[GRID]            [x*NBY+y]
// H(x,y) = A_h(x,y) + sum_{x'<x} B_h(x',y); same for V.

__global__ void init_ws(float4* __restrict__ bbox, unsigned* __restrict__ count) {
    int t = blockIdx.x * 256 + threadIdx.x;
    if (t < NUM_NETS) {
        float inf = __uint_as_float(0x7F800000u);
        bbox[t] = make_float4(inf, inf, 0.0f, 0.0f);
    }
    if (t < 256 * 16) count[t] = 0u;
}

// ---------------------------------------------------------------- pin phase
// One thread per pin slot; wave-segmented min/max scan (net_id sorted along
// slots). Nets fully contained in one wave -> single plain float4 store.
// Only wave-crossing nets use atomics.
__global__ void pin_bbox(const float* __restrict__ pin_pos,
                         const int* __restrict__ netpin_start,
                         const int* __restrict__ flat_netpin,
                         float4* __restrict__ bbox) {
    int t = blockIdx.x * 256 + threadIdx.x;
    int key = -4;              // (net<<1)|head_seen ; invalid sentinel
    int net = -1, segend = -1;
    float xmn = 3.4e38f, xmx = -3.4e38f, ymn = 3.4e38f, ymx = -3.4e38f;
    if (t < NUM_PINS) {
        int lo = 0, hi = NUM_NETS + 1;
        while (lo < hi) {
            int mid = (lo + hi) >> 1;
            if (netpin_start[mid] <= t) lo = mid + 1; else hi = mid;
        }
        net = min(lo - 1, NUM_NETS - 1);
        int s = netpin_start[net];
        segend = netpin_start[net + 1];
        key = (net << 1) | (s == t ? 1 : 0);
        int p = flat_netpin[t];
        float px = pin_pos[p];
        float py = pin_pos[NUM_PINS + p];
        xmn = px; xmx = px; ymn = py; ymx = py;
    }
    int lane = threadIdx.x & 63;
    for (int d = 1; d < 64; d <<= 1) {
        int   ku = __shfl_up(key, d);
        float a  = __shfl_up(xmn, d);
        float b  = __shfl_up(xmx, d);
        float c  = __shfl_up(ymn, d);
        float e  = __shfl_up(ymx, d);
        if (lane >= d && (ku >> 1) == (key >> 1)) {
            xmn = fminf(xmn, a); xmx = fmaxf(xmx, b);
            ymn = fminf(ymn, c); ymx = fmaxf(ymx, e);
            key |= (ku & 1);
        }
    }
    int nextkey = __shfl_down(key, 1);
    if (t >= NUM_PINS || net < 0) return;
    bool netchg = (lane == 63) ? false : ((nextkey >> 1) != (key >> 1));
    bool tail   = (lane == 63) || netchg;
    if (!tail) return;
    bool true_end  = netchg || (segend == t + 1);
    bool contained = (key & 1) != 0;
    if (contained && true_end) {
        bbox[net] = make_float4(xmn, ymn, xmx, ymx);   // sole writer
    } else {
        unsigned* b = (unsigned*)(bbox + net);
        atomicMin(b + 0, __float_as_uint(xmn));   // coords >= 0: uint order ok
        atomicMin(b + 1, __float_as_uint(ymn));
        atomicMax(b + 2, __float_as_uint(xmx));
        atomicMax(b + 3, __float_as_uint(ymx));
    }
}

// ---------------------------------------------------------------- bucketing
// One thread per net: append (net<<1)|side to row buckets bxl and bxh.
__global__ void scatter_nets(const float4* __restrict__ bbox,
                             unsigned* __restrict__ count,
                             unsigned* __restrict__ entries) {
    int n = blockIdx.x * 256 + threadIdx.x;
    if (n >= NUM_NETS) return;
    float4 b = bbox[n];
    float span_x = b.z - b.x, span_y = b.w - b.y;   // empty net -> -inf
    bool h = span_y > EPSV, v = span_x > EPSV;
    if (!h && !v) return;
    int bxl = min((int)(b.x * INV_BS), NBX - 1);
    int bxh = min((int)(b.z * INV_BS), NBX - 1);
    unsigned p0 = atomicAdd(count + bxl * 16, 1u);
    if (p0 < CAP) entries[bxl * CAP + p0] = (unsigned)(n << 1);
    unsigned p1 = atomicAdd(count + bxh * 16, 1u);
    if (p1 < CAP) entries[bxh * CAP + p1] = (unsigned)(n << 1) | 1u;
}

// ---------------------------------------------------------------- splat phase
// One block per bx row; processes only its bucket (~780 entries avg).
// LDS accumulation, in-block y-scan, transposed A/B emit. No global atomics.
__global__ __launch_bounds__(1024) void splat_rows(
        const float4* __restrict__ bbox,
        const unsigned* __restrict__ count,
        const unsigned* __restrict__ entries,
        float* __restrict__ A_hT, float* __restrict__ B_hT,
        float* __restrict__ A_vT, float* __restrict__ B_vT) {
    int bx = blockIdx.x;
    int t  = threadIdx.x;
    __shared__ float F[8][NBY];  // 0 P_h, 1 CX_h, 2 CY_h, 3 Q_h, 4..7 same V
    for (int i = t; i < 8 * NBY; i += 1024) ((float*)F)[i] = 0.0f;
    __syncthreads();

    int cnt = (int)min(count[bx * 16], (unsigned)CAP);
    for (int i = t; i < cnt; i += 1024) {
        unsigned e = entries[bx * CAP + i];
        int n = (int)(e >> 1), side = (int)(e & 1u);
        float4 b = bbox[n];
        float span_x = b.z - b.x, span_y = b.w - b.y;
        float coef_h = (span_y > EPSV) ? 1.0f / span_y : 0.0f;
        float coef_v = (span_x > EPSV) ? 1.0f / span_x : 0.0f;
        int byl = min((int)(b.y * INV_BS), NBY - 1);
        int byh = min((int)(b.w * INV_BS), NBY - 1);
        float ryl = (float)(byl + 1) * BSX - b.y;
        float ryh = (float)(byh + 1) * BSX - b.w;
        float rx, s0;
        if (side == 0) {
            int bxl = min((int)(b.x * INV_BS), NBX - 1);
            rx = (float)(bxl + 1) * BSX - b.x; s0 = 1.0f;
        } else {
            int bxh = min((int)(b.z * INV_BS), NBX - 1);
            rx = (float)(bxh + 1) * BSX - b.z; s0 = -1.0f;
        }
        if (coef_h != 0.0f) {
            float w0 = s0 * coef_h, w1 = -s0 * coef_h;
            atomicAdd(&F[0][byl], w0 * rx  * ryl);
            atomicAdd(&F[1][byl], w0 * rx  * BSX);
            atomicAdd(&F[2][byl], w0 * BSX * ryl);
            atomicAdd(&F[3][byl], w0 * BSX * BSX);
            atomicAdd(&F[0][byh], w1 * rx  * ryh);
            atomicAdd(&F[1][byh], w1 * rx  * BSX);
            atomicAdd(&F[2][byh], w1 * BSX * ryh);
            atomicAdd(&F[3][byh], w1 * BSX * BSX);
        }
        if (coef_v != 0.0f) {
            float w0 = s0 * coef_v, w1 = -s0 * coef_v;
            atomicAdd(&F[4][byl], w0 * rx  * ryl);
            atomicAdd(&F[5][byl], w0 * rx  * BSX);
            atomicAdd(&F[6][byl], w0 * BSX * ryl);
            atomicAdd(&F[7][byl], w0 * BSX * BSX);
            atomicAdd(&F[4][byh], w1 * rx  * ryh);
            atomicAdd(&F[5][byh], w1 * rx  * BSX);
            atomicAdd(&F[6][byh], w1 * BSX * ryh);
            atomicAdd(&F[7][byh], w1 * BSX * BSX);
        }
    }
    __syncthreads();

    // In-block inclusive y-scan of fields 1,3,5,7 (CX_h, Q_h, CX_v, Q_v).
    int g = t >> 8, y = t & 255;
    float* f = F[2 * g + 1];
    for (int d = 1; d < 256; d <<= 1) {
        float add = (y >= d) ? f[y - d] : 0.0f;
        __syncthreads();
        f[y] += add;
        __syncthreads();
    }
    // A = P + exclusive(CX); B = CY + exclusive(Q). Emit transposed.
    float ex  = (y > 0) ? F[2 * g + 1][y - 1] : 0.0f;
    float val = F[2 * g][y] + ex;
    float* o  = (g == 0) ? A_hT : (g == 1) ? B_hT : (g == 2) ? A_vT : B_vT;
    o[y * NBX + bx] = val;
}

// ---------------------------------------------------------------- x-scan+util
// One block per y, thread per x. Coalesced reads from transposed arrays.
__global__ void scan_x_util(const float* __restrict__ A_hT, const float* __restrict__ B_hT,
                            const float* __restrict__ A_vT, const float* __restrict__ B_vT,
                            float* __restrict__ util) {
    int y = blockIdx.x, x = threadIdx.x;
    int idxT = y * NBX + x;
    __shared__ float2 tmp[NBX];
    tmp[x] = make_float2(B_hT[idxT], B_vT[idxT]);
    __syncthreads();
    for (int d = 1; d < 256; d <<= 1) {
        float2 add = (x >= d) ? tmp[x - d] : make_float2(0.f, 0.f);
        __syncthreads();
        tmp[x].x += add.x; tmp[x].y += add.y;
        __syncthreads();
    }
    float2 ex = (x > 0) ? tmp[x - 1] : make_float2(0.f, 0.f);
    float H = A_hT[idxT] + ex.x;
    float V = A_vT[idxT] + ex.y;
    float u = fmaxf(H, V) * (1.0f / (BIN_AREA * 1.5f));
    util[x * NBY + y] = fminf(fmaxf(u, 0.5f), 2.0f);
}

// ---------------------------------------------------------------- node phase
__global__ void node_area(const float* __restrict__ pos,
                          const float* __restrict__ nsx,
                          const float* __restrict__ nsy,
                          const float* __restrict__ util,
                          float* __restrict__ out) {
    int m = blockIdx.x * 256 + threadIdx.x;
    if (m >= NUM_MOVABLE) return;
    float xl = pos[m];
    float yl = pos[NUM_NODES + m];
    float xh = xl + nsx[m];
    float yh = yl + nsy[m];
    int bx0 = max(0, min((int)(xl * INV_BS), NBX - 1));
    int bx1 = max(0, min((int)(xh * INV_BS), NBX - 1));
    int by0 = max(0, min((int)(yl * INV_BS), NBY - 1));
    int by1 = max(0, min((int)(yh * INV_BS), NBY - 1));
    float acc = 0.0f;
    for (int bx = bx0; bx <= bx1; ++bx) {
        float ox = fminf(xh, (float)(bx + 1) * BSX) - fmaxf(xl, (float)bx * BSX);
        if (ox <= 0.0f) continue;
        const float* urow = util + bx * NBY;
        float inner = 0.0f;
        for (int by = by0; by <= by1; ++by) {
            float oy = fminf(yh, (float)(by + 1) * BSX) - fmaxf(yl, (float)by * BSX);
            if (oy > 0.0f) inner += oy * urow[by];
        }
        acc += ox * inner;
    }
    out[m] = acc;
}

extern "C" void kernel_launch(void* const* d_in, const int* in_sizes, int n_in,
                              void* d_out, int out_size, void* d_ws, size_t ws_size,
                              hipStream_t stream) {
    const float* pos          = (const float*)d_in[0];
    const float* pin_pos      = (const float*)d_in[1];
    const float* node_size_x  = (const float*)d_in[2];
    const float* node_size_y  = (const float*)d_in[3];
    const int*   netpin_start = (const int*)d_in[4];
    const int*   flat_netpin  = (const int*)d_in[5];

    float4*   bbox    = (float4*)d_ws;                       // 1.6 MB
    unsigned* count   = (unsigned*)(bbox + NUM_NETS);        // 16 KB
    unsigned* entries = count + 256 * 16;                    // 2 MB
    float*    A_hT    = (float*)(entries + 256 * CAP);       // 4 x 256 KB
    float*    B_hT    = A_hT + GRID;
    float*    A_vT    = B_hT + GRID;
    float*    B_vT    = A_vT + GRID;
    float*    util    = B_vT + GRID;                         // 256 KB
    float*    out     = (float*)d_out;

    init_ws<<<(NUM_NETS + 255) / 256, 256, 0, stream>>>(bbox, count);
    pin_bbox<<<(NUM_PINS + 255) / 256, 256, 0, stream>>>(
        pin_pos, netpin_start, flat_netpin, bbox);
    scatter_nets<<<(NUM_NETS + 255) / 256, 256, 0, stream>>>(bbox, count, entries);
    splat_rows<<<NBX, 1024, 0, stream>>>(bbox, count, entries, A_hT, B_hT, A_vT, B_vT);
    scan_x_util<<<NBY, NBX, 0, stream>>>(A_hT, B_hT, A_vT, B_vT, util);
    node_area<<<(NUM_MOVABLE + 255) / 256, 256, 0, stream>>>(
        pos, node_size_x, node_size_y, util, out);
}

// Round 6
// 131.572 us; speedup vs baseline: 1.2818x; 1.2818x over previous
//
#include <hip/hip_runtime.h>

#define NUM_NODES   120000
#define NUM_MOVABLE 100000
#define NUM_NETS    100000
#define NUM_PINS    400000
#define NBX 256
#define NBY 256
#define GRID (NBX*NBY)
#define CAP 2048            // per-row bucket capacity (expected max ~1600)
#define SC_BLOCKS 32
#define SC_PER 4            // nets per thread in scatter (32*1024*4 >= 100000)

constexpr float BSX      = 1000.0f / 256.0f;   // 3.90625 exact in binary
constexpr float INV_BS   = 256.0f / 1000.0f;
constexpr float BIN_AREA = BSX * BSX;
constexpr float EPSV     = 1e-6f;

// Workspace layout:
//   bbox:    float4[NUM_NETS]       {xmn, ymn, xmx, ymx}
//   count:   u32[256*16]            per-row cursor, line-padded (stride 16)
//   entries: u32[256*CAP]           (net<<1)|side per row bucket
//   A_hT,B_hT,A_vT,B_vT: float[GRID] transposed [y*NBX+x]
//   util:    float[GRID]            [x*NBY+y]
// H(x,y) = A_h(x,y) + sum_{x'<x} B_h(x',y); same for V.

__global__ void init_ws(float4* __restrict__ bbox, unsigned* __restrict__ count) {
    int t = blockIdx.x * 256 + threadIdx.x;
    if (t < NUM_NETS) {
        float inf = __uint_as_float(0x7F800000u);
        bbox[t] = make_float4(inf, inf, 0.0f, 0.0f);
    }
    if (t < 256 * 16) count[t] = 0u;
}

// ---------------------------------------------------------------- pin phase
// Per-block: 2 binary searches bound the nets this block's 256 slots touch,
// stage those netpin_start entries in LDS, per-thread search is 9 LDS steps
// (was 17 dependent global loads). Then wave-segmented min/max scan;
// contained nets -> one plain float4 store; wave-crossing nets -> atomics.
__global__ void pin_bbox(const float* __restrict__ pin_pos,
                         const int* __restrict__ netpin_start,
                         const int* __restrict__ flat_netpin,
                         float4* __restrict__ bbox) {
    __shared__ int snp[260];
    __shared__ int sbound[2];
    int B0 = blockIdx.x * 256;
    int t  = B0 + threadIdx.x;
    if (threadIdx.x < 2) {
        int q = (threadIdx.x == 0) ? B0 : min(B0 + 255, NUM_PINS - 1);
        int lo = 0, hi = NUM_NETS + 1;
        while (lo < hi) {
            int mid = (lo + hi) >> 1;
            if (netpin_start[mid] <= q) lo = mid + 1; else hi = mid;
        }
        sbound[threadIdx.x] = min(lo - 1, NUM_NETS - 1);
    }
    __syncthreads();
    int netlo = sbound[0];
    int cnt   = sbound[1] - netlo + 2;       // entries netlo .. nethi+1
    for (int i = threadIdx.x; i < cnt; i += 256) snp[i] = netpin_start[netlo + i];
    __syncthreads();

    int key = -4;              // (net<<1)|head_seen ; invalid sentinel
    int net = -1, segend = -1;
    float xmn = 3.4e38f, xmx = -3.4e38f, ymn = 3.4e38f, ymx = -3.4e38f;
    if (t < NUM_PINS) {
        int lo = 0, hi = cnt;
        while (lo < hi) {
            int mid = (lo + hi) >> 1;
            if (snp[mid] <= t) lo = mid + 1; else hi = mid;
        }
        int li = lo - 1;                     // local net index
        net    = netlo + li;
        segend = snp[li + 1];
        key    = (net << 1) | (snp[li] == t ? 1 : 0);
        int p = flat_netpin[t];
        float px = pin_pos[p];
        float py = pin_pos[NUM_PINS + p];
        xmn = px; xmx = px; ymn = py; ymx = py;
    }
    int lane = threadIdx.x & 63;
    for (int d = 1; d < 64; d <<= 1) {
        int   ku = __shfl_up(key, d);
        float a  = __shfl_up(xmn, d);
        float b  = __shfl_up(xmx, d);
        float c  = __shfl_up(ymn, d);
        float e  = __shfl_up(ymx, d);
        if (lane >= d && (ku >> 1) == (key >> 1)) {
            xmn = fminf(xmn, a); xmx = fmaxf(xmx, b);
            ymn = fminf(ymn, c); ymx = fmaxf(ymx, e);
            key |= (ku & 1);
        }
    }
    int nextkey = __shfl_down(key, 1);
    if (t >= NUM_PINS || net < 0) return;
    bool netchg = (lane == 63) ? false : ((nextkey >> 1) != (key >> 1));
    bool tail   = (lane == 63) || netchg;
    if (!tail) return;
    bool true_end  = netchg || (segend == t + 1);
    bool contained = (key & 1) != 0;
    if (contained && true_end) {
        bbox[net] = make_float4(xmn, ymn, xmx, ymx);   // sole writer
    } else {
        unsigned* b = (unsigned*)(bbox + net);
        atomicMin(b + 0, __float_as_uint(xmn));   // coords >= 0: uint order ok
        atomicMin(b + 1, __float_as_uint(ymn));
        atomicMax(b + 2, __float_as_uint(xmx));
        atomicMax(b + 3, __float_as_uint(ymx));
    }
}

// ---------------------------------------------------------------- bucketing
// Block-aggregated scatter: LDS histogram -> one global atomicAdd per
// (block,row) to reserve a range -> write entries into reserved slots.
// Global atomics: 200k -> ~8.2k (32 per address max).
__global__ __launch_bounds__(1024) void scatter_nets(
        const float4* __restrict__ bbox,
        unsigned* __restrict__ count,
        unsigned* __restrict__ entries) {
    __shared__ unsigned hist[256];
    __shared__ unsigned base[256];
    __shared__ unsigned cur[256];
    int t = threadIdx.x;
    if (t < 256) hist[t] = 0u;
    __syncthreads();
    int start = blockIdx.x * (1024 * SC_PER);
    unsigned packed[SC_PER];
    #pragma unroll
    for (int k = 0; k < SC_PER; ++k) {
        int n = start + k * 1024 + t;
        packed[k] = 0xFFFFFFFFu;
        if (n < NUM_NETS) {
            float4 b = bbox[n];
            if ((b.w - b.y) > EPSV || (b.z - b.x) > EPSV) {
                unsigned bxl = (unsigned)min((int)(b.x * INV_BS), NBX - 1);
                unsigned bxh = (unsigned)min((int)(b.z * INV_BS), NBX - 1);
                packed[k] = bxl | (bxh << 8);
                atomicAdd(&hist[bxl], 1u);
                atomicAdd(&hist[bxh], 1u);
            }
        }
    }
    __syncthreads();
    if (t < 256) {
        unsigned c = hist[t];
        base[t] = c ? atomicAdd(&count[t * 16], c) : 0u;
        cur[t]  = 0u;
    }
    __syncthreads();
    #pragma unroll
    for (int k = 0; k < SC_PER; ++k) {
        if (packed[k] != 0xFFFFFFFFu) {
            int n = start + k * 1024 + t;
            unsigned bxl = packed[k] & 255u, bxh = (packed[k] >> 8) & 255u;
            unsigned p0 = base[bxl] + atomicAdd(&cur[bxl], 1u);
            if (p0 < CAP) entries[bxl * CAP + p0] = (unsigned)(n << 1);
            unsigned p1 = base[bxh] + atomicAdd(&cur[bxh], 1u);
            if (p1 < CAP) entries[bxh * CAP + p1] = (unsigned)(n << 1) | 1u;
        }
    }
}

// ---------------------------------------------------------------- splat phase
// One block per bx row; processes only its bucket (~780 entries avg).
// LDS accumulation, in-block y-scan, transposed A/B emit. No global atomics.
__global__ __launch_bounds__(1024) void splat_rows(
        const float4* __restrict__ bbox,
        const unsigned* __restrict__ count,
        const unsigned* __restrict__ entries,
        float* __restrict__ A_hT, float* __restrict__ B_hT,
        float* __restrict__ A_vT, float* __restrict__ B_vT) {
    int bx = blockIdx.x;
    int t  = threadIdx.x;
    __shared__ float F[8][NBY];  // 0 P_h, 1 CX_h, 2 CY_h, 3 Q_h, 4..7 same V
    for (int i = t; i < 8 * NBY; i += 1024) ((float*)F)[i] = 0.0f;
    __syncthreads();

    int cnt = (int)min(count[bx * 16], (unsigned)CAP);
    for (int i = t; i < cnt; i += 1024) {
        unsigned e = entries[bx * CAP + i];
        int n = (int)(e >> 1), side = (int)(e & 1u);
        float4 b = bbox[n];
        float span_x = b.z - b.x, span_y = b.w - b.y;
        float coef_h = (span_y > EPSV) ? 1.0f / span_y : 0.0f;
        float coef_v = (span_x > EPSV) ? 1.0f / span_x : 0.0f;
        int byl = min((int)(b.y * INV_BS), NBY - 1);
        int byh = min((int)(b.w * INV_BS), NBY - 1);
        float ryl = (float)(byl + 1) * BSX - b.y;
        float ryh = (float)(byh + 1) * BSX - b.w;
        float rx, s0;
        if (side == 0) {
            int bxl = min((int)(b.x * INV_BS), NBX - 1);
            rx = (float)(bxl + 1) * BSX - b.x; s0 = 1.0f;
        } else {
            int bxh = min((int)(b.z * INV_BS), NBX - 1);
            rx = (float)(bxh + 1) * BSX - b.z; s0 = -1.0f;
        }
        if (coef_h != 0.0f) {
            float w0 = s0 * coef_h, w1 = -s0 * coef_h;
            atomicAdd(&F[0][byl], w0 * rx  * ryl);
            atomicAdd(&F[1][byl], w0 * rx  * BSX);
            atomicAdd(&F[2][byl], w0 * BSX * ryl);
            atomicAdd(&F[3][byl], w0 * BSX * BSX);
            atomicAdd(&F[0][byh], w1 * rx  * ryh);
            atomicAdd(&F[1][byh], w1 * rx  * BSX);
            atomicAdd(&F[2][byh], w1 * BSX * ryh);
            atomicAdd(&F[3][byh], w1 * BSX * BSX);
        }
        if (coef_v != 0.0f) {
            float w0 = s0 * coef_v, w1 = -s0 * coef_v;
            atomicAdd(&F[4][byl], w0 * rx  * ryl);
            atomicAdd(&F[5][byl], w0 * rx  * BSX);
            atomicAdd(&F[6][byl], w0 * BSX * ryl);
            atomicAdd(&F[7][byl], w0 * BSX * BSX);
            atomicAdd(&F[4][byh], w1 * rx  * ryh);
            atomicAdd(&F[5][byh], w1 * rx  * BSX);
            atomicAdd(&F[6][byh], w1 * BSX * ryh);
            atomicAdd(&F[7][byh], w1 * BSX * BSX);
        }
    }
    __syncthreads();

    // In-block inclusive y-scan of fields 1,3,5,7 (CX_h, Q_h, CX_v, Q_v).
    int g = t >> 8, y = t & 255;
    float* f = F[2 * g + 1];
    for (int d = 1; d < 256; d <<= 1) {
        float add = (y >= d) ? f[y - d] : 0.0f;
        __syncthreads();
        f[y] += add;
        __syncthreads();
    }
    // A = P + exclusive(CX); B = CY + exclusive(Q). Emit transposed.
    float ex  = (y > 0) ? F[2 * g + 1][y - 1] : 0.0f;
    float val = F[2 * g][y] + ex;
    float* o  = (g == 0) ? A_hT : (g == 1) ? B_hT : (g == 2) ? A_vT : B_vT;
    o[y * NBX + bx] = val;
}

// ---------------------------------------------------------------- x-scan+util
// One block per y, thread per x. Coalesced reads from transposed arrays.
__global__ void scan_x_util(const float* __restrict__ A_hT, const float* __restrict__ B_hT,
                            const float* __restrict__ A_vT, const float* __restrict__ B_vT,
                            float* __restrict__ util) {
    int y = blockIdx.x, x = threadIdx.x;
    int idxT = y * NBX + x;
    __shared__ float2 tmp[NBX];
    tmp[x] = make_float2(B_hT[idxT], B_vT[idxT]);
    __syncthreads();
    for (int d = 1; d < 256; d <<= 1) {
        float2 add = (x >= d) ? tmp[x - d] : make_float2(0.f, 0.f);
        __syncthreads();
        tmp[x].x += add.x; tmp[x].y += add.y;
        __syncthreads();
    }
    float2 ex = (x > 0) ? tmp[x - 1] : make_float2(0.f, 0.f);
    float H = A_hT[idxT] + ex.x;
    float V = A_vT[idxT] + ex.y;
    float u = fmaxf(H, V) * (1.0f / (BIN_AREA * 1.5f));
    util[x * NBY + y] = fminf(fmaxf(u, 0.5f), 2.0f);
}

// ---------------------------------------------------------------- node phase
__global__ void node_area(const float* __restrict__ pos,
                          const float* __restrict__ nsx,
                          const float* __restrict__ nsy,
                          const float* __restrict__ util,
                          float* __restrict__ out) {
    int m = blockIdx.x * 256 + threadIdx.x;
    if (m >= NUM_MOVABLE) return;
    float xl = pos[m];
    float yl = pos[NUM_NODES + m];
    float xh = xl + nsx[m];
    float yh = yl + nsy[m];
    int bx0 = max(0, min((int)(xl * INV_BS), NBX - 1));
    int bx1 = max(0, min((int)(xh * INV_BS), NBX - 1));
    int by0 = max(0, min((int)(yl * INV_BS), NBY - 1));
    int by1 = max(0, min((int)(yh * INV_BS), NBY - 1));
    float acc = 0.0f;
    for (int bx = bx0; bx <= bx1; ++bx) {
        float ox = fminf(xh, (float)(bx + 1) * BSX) - fmaxf(xl, (float)bx * BSX);
        if (ox <= 0.0f) continue;
        const float* urow = util + bx * NBY;
        float inner = 0.0f;
        for (int by = by0; by <= by1; ++by) {
            float oy = fminf(yh, (float)(by + 1) * BSX) - fmaxf(yl, (float)by * BSX);
            if (oy > 0.0f) inner += oy * urow[by];
        }
        acc += ox * inner;
    }
    out[m] = acc;
}

extern "C" void kernel_launch(void* const* d_in, const int* in_sizes, int n_in,
                              void* d_out, int out_size, void* d_ws, size_t ws_size,
                              hipStream_t stream) {
    const float* pos          = (const float*)d_in[0];
    const float* pin_pos      = (const float*)d_in[1];
    const float* node_size_x  = (const float*)d_in[2];
    const float* node_size_y  = (const float*)d_in[3];
    const int*   netpin_start = (const int*)d_in[4];
    const int*   flat_netpin  = (const int*)d_in[5];

    float4*   bbox    = (float4*)d_ws;                       // 1.6 MB
    unsigned* count   = (unsigned*)(bbox + NUM_NETS);        // 16 KB
    unsigned* entries = count + 256 * 16;                    // 2 MB
    float*    A_hT    = (float*)(entries + 256 * CAP);       // 4 x 256 KB
    float*    B_hT    = A_hT + GRID;
    float*    A_vT    = B_hT + GRID;
    float*    B_vT    = A_vT + GRID;
    float*    util    = B_vT + GRID;                         // 256 KB
    float*    out     = (float*)d_out;

    init_ws<<<(NUM_NETS + 255) / 256, 256, 0, stream>>>(bbox, count);
    pin_bbox<<<(NUM_PINS + 255) / 256, 256, 0, stream>>>(
        pin_pos, netpin_start, flat_netpin, bbox);
    scatter_nets<<<SC_BLOCKS, 1024, 0, stream>>>(bbox, count, entries);
    splat_rows<<<NBX, 1024, 0, stream>>>(bbox, count, entries, A_hT, B_hT, A_vT, B_vT);
    scan_x_util<<<NBY, NBX, 0, stream>>>(A_hT, B_hT, A_vT, B_vT, util);
    node_area<<<(NUM_MOVABLE + 255) / 256, 256, 0, stream>>>(
        pos, node_size_x, node_size_y, util, out);
}